// Round 13
// baseline (432.605 us; speedup 1.0000x reference)
//
#include <hip/hip_runtime.h>
#include <hip/hip_bf16.h>

#define NN 20000
#define NE 100000
#define NINC (2 * NE)        // 200000 incidences
#define NB (NINC / 16)       // 12500 incidence blocks, exactly full
#define SLOTS 16
#define FSTRIDE 2056   // u16 per slot: 2048 + 8 pad -> slot base advances 4 banks

typedef __attribute__((ext_vector_type(8))) short bf16x8;
typedef __attribute__((ext_vector_type(4))) float f32x4;
typedef __attribute__((ext_vector_type(16))) float f32x16;
typedef __attribute__((ext_vector_type(2))) unsigned uint2v;
typedef __attribute__((ext_vector_type(4))) unsigned uint4v;

// ---- ws layout ----
#define WS_RBFT 0u
#define WS_FLAG 131072u
#define WS_OFF  131328u                          // uint off[NN+1]
#define WS_CUR  (WS_OFF + 4u*(NN+1))             // uint cur[NN]
#define WS_CNT  (WS_CUR + 4u*NN)                 // uint cnt[NN]
#define WS_INC  (WS_CNT + 4u*NN)                 // uint inc[2*NE]
#define WS_NODE (WS_INC + 4u*NINC)               // uint nodeOf[2*NE]
#define WS_CSR_END ((size_t)WS_NODE + 4u*NINC)
#define WS_XT   ((WS_CSR_END + 4095u) & ~(size_t)4095u)
#define WS_XT_END (WS_XT + (size_t)NN * 2048u * 2u)   // bf16 xT[n][f][k]
#define WS_PB   ((WS_XT_END + 4095u) & ~(size_t)4095u)
#define WS_PB_END (WS_PB + (size_t)NB * 2u * 2048u)   // bf16 pbuf[NB][2][1024]

__device__ __forceinline__ unsigned short f2bf(float f) {
    unsigned u = __float_as_uint(f);
    u += 0x7fffu + ((u >> 16) & 1u);
    return (unsigned short)(u >> 16);
}

__device__ __forceinline__ unsigned pack2bf(float a, float b) {
    union { __hip_bfloat162 h; unsigned u; } q;
    q.h = __float22bfloat162_rn(make_float2(a, b));
    return q.u;
}

__device__ __forceinline__ float bf2f(unsigned s) {
    return __uint_as_float(s << 16);
}

__device__ __forceinline__ bf16x8 bneg8(bf16x8 v) {
    union { bf16x8 s; uint4v u; } a; a.s = v;
    a.u[0] ^= 0x80008000u; a.u[1] ^= 0x80008000u;
    a.u[2] ^= 0x80008000u; a.u[3] ^= 0x80008000u;
    return a.s;
}

// RbfT bf16 [pos(2048)][a(32)]; zero the int64-detect flag
__global__ void prep_rbf_kernel(const float* __restrict__ R, unsigned short* __restrict__ RbfT,
                                int* __restrict__ flag) {
    int idx = blockIdx.x * blockDim.x + threadIdx.x;
    if (idx == 0) *flag = 0;
    if (idx >= 2048 * 32) return;
    int pos = idx >> 5;
    int a = idx & 31;
    RbfT[idx] = f2bf(R[a * 2048 + pos]);
}

__global__ void detect_kernel(const unsigned* __restrict__ w, int* __restrict__ flag) {
    int k = blockIdx.x * blockDim.x + threadIdx.x;
    if (k < NE && w[2 * k + 1] != 0) atomicOr(flag, 1);
}

__device__ __forceinline__ void decode_edge(const void* eidx, int use64, int e, int& src, int& dst) {
    if (use64) {
        const long long* p = (const long long*)eidx;
        src = (int)p[e]; dst = (int)p[NE + e];
    } else {
        const int* p = (const int*)eidx;
        src = p[e]; dst = p[NE + e];
    }
}

__global__ void count_kernel(const void* __restrict__ eidx, const int* __restrict__ flag,
                             unsigned* __restrict__ cnt) {
    int e = blockIdx.x * blockDim.x + threadIdx.x;
    if (e >= NE) return;
    int src, dst;
    decode_edge(eidx, *flag == 0, e, src, dst);
    if ((unsigned)src < NN) atomicAdd(&cnt[src], 1u);
    if ((unsigned)dst < NN) atomicAdd(&cnt[dst], 1u);
}

__global__ __launch_bounds__(1024) void scan_kernel(const unsigned* __restrict__ cnt,
                                                    unsigned* __restrict__ off,
                                                    unsigned* __restrict__ cur) {
    __shared__ unsigned sd[1024];
    const int t = threadIdx.x;
    unsigned vals[20];
    unsigned s = 0;
#pragma unroll
    for (int j = 0; j < 20; ++j) {
        int idx = t * 20 + j;
        unsigned v = (idx < NN) ? cnt[idx] : 0u;
        vals[j] = s; s += v;
    }
    sd[t] = s;
    __syncthreads();
    for (int d = 1; d < 1024; d <<= 1) {
        unsigned v = (t >= d) ? sd[t - d] : 0u;
        __syncthreads();
        sd[t] += v;
        __syncthreads();
    }
    unsigned base = (t > 0) ? sd[t - 1] : 0u;
#pragma unroll
    for (int j = 0; j < 20; ++j) {
        int idx = t * 20 + j;
        if (idx < NN) { unsigned o = base + vals[j]; off[idx] = o; cur[idx] = o; }
    }
    if (t == 1023) off[NN] = sd[1023];
}

__global__ void scatter_kernel(const void* __restrict__ eidx, const int* __restrict__ flag,
                               unsigned* __restrict__ cur, unsigned* __restrict__ inc,
                               unsigned* __restrict__ nodeOf) {
    int e = blockIdx.x * blockDim.x + threadIdx.x;
    if (e >= NE) return;
    int src, dst;
    decode_edge(eidx, *flag == 0, e, src, dst);
    if ((unsigned)src < NN) { unsigned p = atomicAdd(&cur[src], 1u); inc[p] = (unsigned)e; nodeOf[p] = (unsigned)src; }
    if ((unsigned)dst < NN) { unsigned p = atomicAdd(&cur[dst], 1u); inc[p] = (unsigned)e | 0x80000000u; nodeOf[p] = (unsigned)dst; }
}

// ---- transpose+convert: xT[n][f][k] bf16 from x[n][k][f] f32 (4 nodes/block) ----
__global__ __launch_bounds__(256) void xpose_kernel(const float* __restrict__ x,
                                                    unsigned short* __restrict__ xT) {
    __shared__ float tile[4][32][33];
    const int t = threadIdx.x, sub = t >> 6, lane = t & 63;
    const int n = blockIdx.x * 4 + sub;
    const int row = lane >> 1, half = (lane & 1) * 16;
    const float* xp = x + (size_t)n * 1024 + row * 32 + half;
    float* tp = &tile[sub][row][half];
#pragma unroll
    for (int c = 0; c < 4; ++c)
        *(f32x4*)(tp + 4 * c) = *(const f32x4*)(xp + 4 * c);
    __syncthreads();
    const int f = lane >> 1, k0 = (lane & 1) * 16;
    unsigned w[8];
#pragma unroll
    for (int m = 0; m < 8; ++m) {
        unsigned lo = (unsigned)f2bf(tile[sub][k0 + 2 * m][f]);
        unsigned hi = (unsigned)f2bf(tile[sub][k0 + 2 * m + 1][f]);
        w[m] = lo | (hi << 16);
    }
    unsigned short* op = xT + (size_t)n * 2048 + f * 32 + k0;
    uint4v v0 = {w[0], w[1], w[2], w[3]};
    uint4v v1 = {w[4], w[5], w[6], w[7]};
    *(uint4v*)op = v0;
    *(uint4v*)(op + 8) = v1;
}

// ---- Incidence-block kernel: 16 incidences/block, zero atomics, 2 barriers.
// Slot metadata derived uniformly from inc[]/nodeOf[] (no LDS fill stage):
// phase A per-lane, phase B per-wave-uniform, segsum block-uniform walks.
__global__ __launch_bounds__(256, 2) void sheaf_inc(
    const unsigned short* __restrict__ xTbuf,
    const void* __restrict__ eidx_raw,
    const float* __restrict__ ea,
    const unsigned short* __restrict__ RbfT,
    const int* __restrict__ flag,
    const unsigned* __restrict__ off,
    const unsigned* __restrict__ inc,
    const unsigned* __restrict__ nodeOf,
    float* __restrict__ out,
    unsigned short* __restrict__ pbuf)
{
    __shared__ __align__(16) unsigned short F_lds[SLOTS * FSTRIDE]; // 64.25KB; F then per-slot y (f32)
    __shared__ __align__(16) unsigned dx_lds32[4 * 512];            // per-wave [rowpair(16)][col(32)] u32

    const int b    = blockIdx.x;
    const int p0   = b * 16;
    const int tid  = threadIdx.x;
    const int lane = tid & 63;
    const int wv   = tid >> 6;
    const int use64 = (*flag == 0);

    const int r31 = lane & 31;
    const int hi  = lane >> 5;
    const int kb  = hi * 8;
    unsigned* dx2 = dx_lds32 + wv * 512;

    // ---- per-wave uniform decode + T14 xT prefetch for this wave's 4 slots ----
    int wsrc[4], wdst[4], wside[4];
    bf16x8 pre0[4], pre1[4], pre2[4], pre3[4];
#pragma unroll
    for (int s = 0; s < 4; ++s) {
        const int si = wv + 4 * s;
        const unsigned v = inc[p0 + si];        // uniform per wave -> scalar load
        const int e = (int)(v & 0x7fffffffu);
        int sr, dd; decode_edge(eidx_raw, use64, e, sr, dd);
        if ((unsigned)sr >= NN) sr = 0;
        if ((unsigned)dd >= NN) dd = 0;
        wsrc[s] = sr; wdst[s] = dd; wside[s] = (int)(v >> 31);
        const unsigned short* xls = xTbuf + (size_t)sr * 2048 + r31 * 32 + kb;
        const unsigned short* xrs = xTbuf + (size_t)dd * 2048 + r31 * 32 + kb;
        pre0[s] = *(const bf16x8*)xls;
        pre1[s] = *(const bf16x8*)(xls + 16);
        pre2[s] = *(const bf16x8*)xrs;
        pre3[s] = *(const bf16x8*)(xrs + 16);
    }

    // ---- Phase A (operand-swapped): F[slot][pos] = sum_k ea[slot][k] RbfT[pos][k] ----
    {
        const int slot = lane & 15;          // B col AND C col
        const int ab   = (lane >> 4) * 8;    // k offset
        const int e    = (int)(inc[p0 + slot] & 0x7fffffffu);   // per-lane (16-way broadcast)
        bf16x8 bfrag;
        {
            const float* eap = ea + (size_t)e * 32 + ab;
            f32x4 a0 = *(const f32x4*)eap;
            f32x4 a1 = *(const f32x4*)(eap + 4);
#pragma unroll
            for (int j = 0; j < 4; ++j) { bfrag[j] = (short)f2bf(a0[j]); bfrag[4 + j] = (short)f2bf(a1[j]); }
        }
        unsigned short* fdst = F_lds + slot * FSTRIDE;
        const int pg = (lane >> 4) * 4;      // C rows = pos offsets pg..pg+3 within the 16-tile
#pragma unroll 16
        for (int t = 0; t < 32; ++t) {
            const int pos_base = wv * 512 + t * 16;
            bf16x8 afrag = *(const bf16x8*)(RbfT + (size_t)(pos_base + (lane & 15)) * 32 + ab);
            f32x4 c = {0.f, 0.f, 0.f, 0.f};
            c = __builtin_amdgcn_mfma_f32_16x16x32_bf16(afrag, bfrag, c, 0, 0, 0);
            const int posb = pos_base + pg;          // 4-aligned
            const int side = posb >> 10;
            const int ijb  = posb & 1023;
            const int i    = ijb >> 5;
            const int soff = ijb ^ ((i & 7) << 3);   // XOR bits 3-5; 4-chunk stays contiguous
            uint2v wp = {pack2bf(c[0], c[1]), pack2bf(c[2], c[3])};
            *(uint2v*)(fdst + side * 1024 + soff) = wp;
        }
    }
    __syncthreads();

    // ---- Phase B: wave wv handles slots wv, wv+4, wv+8, wv+12; y -> F_lds[si] (f32) ----
#pragma unroll
    for (int s = 0; s < 4; ++s) {
        const int si = wv + 4 * s;
        const int side = wside[s];

        bf16x8 xlf0 = pre0[s];
        bf16x8 xlf1 = pre1[s];
        bf16x8 xrf0 = bneg8(pre2[s]);
        bf16x8 xrf1 = bneg8(pre3[s]);

        const unsigned short* Fl = F_lds + si * FSTRIDE;
        const unsigned short* Fr = Fl + 1024;
        const int rbase = r31 * 32;
        const int rsw   = (r31 & 7) << 3;
        bf16x8 fl0 = *(const bf16x8*)(Fl + ((rbase + kb) ^ rsw));
        bf16x8 fl1 = *(const bf16x8*)(Fl + ((rbase + 16 + kb) ^ rsw));
        bf16x8 fr0 = *(const bf16x8*)(Fr + ((rbase + kb) ^ rsw));
        bf16x8 fr1 = *(const bf16x8*)(Fr + ((rbase + 16 + kb) ^ rsw));

        f32x16 dacc;
#pragma unroll
        for (int r = 0; r < 16; ++r) dacc[r] = 0.f;
        dacc = __builtin_amdgcn_mfma_f32_32x32x16_bf16(fl0, xlf0, dacc, 0, 0, 0);
        dacc = __builtin_amdgcn_mfma_f32_32x32x16_bf16(fl1, xlf1, dacc, 0, 0, 0);
        dacc = __builtin_amdgcn_mfma_f32_32x32x16_bf16(fr0, xrf0, dacc, 0, 0, 0);
        dacc = __builtin_amdgcn_mfma_f32_32x32x16_bf16(fr1, xrf1, dacc, 0, 0, 0);

        // dx -> LDS row-pair packed (sign via uniform XOR), read back as B-fragment
        const unsigned smask = side ? 0x80008000u : 0u;
#pragma unroll
        for (int m = 0; m < 8; ++m) {
            const int wi = (m & 1) + 4 * (m >> 1) + 2 * hi;   // rowpair index
            dx2[wi * 32 + r31] = pack2bf(dacc[2 * m], dacc[2 * m + 1]) ^ smask;
        }
        unsigned wa[4], wb[4];
#pragma unroll
        for (int m = 0; m < 4; ++m) {
            wa[m] = dx2[(4 * hi + m) * 32 + r31];
            wb[m] = dx2[(8 + 4 * hi + m) * 32 + r31];
        }
        union { uint4v u; bf16x8 s; } pa, pb;
        pa.u = (uint4v){wa[0], wa[1], wa[2], wa[3]};
        pb.u = (uint4v){wb[0], wb[1], wb[2], wb[3]};
        const bf16x8 dxf0 = pa.s, dxf1 = pb.s;

        // y = F_side^T (sgn*dx)
        const unsigned short* Fs = side ? Fr : Fl;
        bf16x8 fT0, fT1;
#pragma unroll
        for (int j = 0; j < 8; ++j) {
            const int k0 = kb + j, k1 = 16 + kb + j;
            fT0[j] = (short)Fs[(k0 * 32 + r31) ^ ((k0 & 7) << 3)];
            fT1[j] = (short)Fs[(k1 * 32 + r31) ^ ((k1 & 7) << 3)];
        }
        f32x16 y;
#pragma unroll
        for (int r = 0; r < 16; ++r) y[r] = 0.f;
        y = __builtin_amdgcn_mfma_f32_32x32x16_bf16(fT0, dxf0, y, 0, 0, 0);
        y = __builtin_amdgcn_mfma_f32_32x32x16_bf16(fT1, dxf1, y, 0, 0, 0);

        // write y over the (now dead) F slot, f32 [32][32]; same-wave ordering only
        float* ybuf = (float*)(F_lds + si * FSTRIDE);
#pragma unroll
        for (int r = 0; r < 16; ++r) {
            const int row = (r & 3) + 8 * (r >> 2) + 4 * hi;
            ybuf[row * 32 + r31] = y[r];
        }
    }
    __syncthreads();

    // ---- segmented sum over slots (runs of equal nodeOf); each thread owns 4 elems ----
    {
        const int e4 = tid * 4;
        int segA = 0;
        while (segA < SLOTS) {
            const int n = (int)nodeOf[p0 + segA];           // uniform
            int segB = segA + 1;
            while (segB < SLOTS && (int)nodeOf[p0 + segB] == n) ++segB;
            f32x4 sum = {0.f, 0.f, 0.f, 0.f};
            for (int s2 = segA; s2 < segB; ++s2) {
                const f32x4 v = *(const f32x4*)((const float*)(F_lds + s2 * FSTRIDE) + e4);
#pragma unroll
                for (int j = 0; j < 4; ++j) sum[j] += v[j];
            }
            const unsigned on = off[n], on1 = off[n + 1];
            const bool complete = ((unsigned)(p0 + segA) == on) && ((unsigned)(p0 + segB) == on1);
            if (complete) {
                *(f32x4*)(out + (size_t)n * 1024 + e4) = sum;
            } else {
                const int idx = (segA == 0) ? 0 : 1;
                unsigned short* pb = pbuf + ((size_t)b * 2 + idx) * 1024;
                uint2v wp = {pack2bf(sum[0], sum[1]), pack2bf(sum[2], sum[3])};
                *(uint2v*)(pb + e4) = wp;
            }
            segA = segB;
        }
    }
}

// ---- epilogue: combine boundary partials; zero deg-0 nodes ----
__global__ __launch_bounds__(256) void combine_kernel(
    const unsigned* __restrict__ off, const unsigned* __restrict__ nodeOf,
    const unsigned short* __restrict__ pbuf, float* __restrict__ out)
{
    const int n = blockIdx.x;
    const int e4 = threadIdx.x * 4;
    const unsigned a = off[n], b = off[n + 1];
    if (a == b) {
        f32x4 z = {0.f, 0.f, 0.f, 0.f};
        *(f32x4*)(out + (size_t)n * 1024 + e4) = z;
        return;
    }
    const unsigned b0 = a >> 4, b1 = (b - 1) >> 4;
    if (b0 == b1) return;   // complete segment; main kernel wrote it
    f32x4 sum = {0.f, 0.f, 0.f, 0.f};
    for (unsigned blk = b0; blk <= b1; ++blk) {
        const int idx = (nodeOf[blk * 16] == (unsigned)n) ? 0 : 1;
        const unsigned short* pb = pbuf + ((size_t)blk * 2 + idx) * 1024;
        uint2v w = *(const uint2v*)(pb + e4);
        sum[0] += bf2f(w[0] & 0xffffu); sum[1] += bf2f(w[0] >> 16);
        sum[2] += bf2f(w[1] & 0xffffu); sum[3] += bf2f(w[1] >> 16);
    }
    *(f32x4*)(out + (size_t)n * 1024 + e4) = sum;
}

// ---- Fallback: proven R10 node-centric kernel (ws too small for pbuf) ----
template<bool XT>
__global__ __launch_bounds__(256, 2) void sheaf_node(
    const float* __restrict__ x,
    const unsigned short* __restrict__ xTbuf,
    const void* __restrict__ eidx_raw,
    const float* __restrict__ ea,
    const unsigned short* __restrict__ RbfT,
    const int* __restrict__ flag,
    const unsigned* __restrict__ off,
    const unsigned* __restrict__ inc,
    float* __restrict__ out)
{
    __shared__ __align__(16) unsigned short F_lds[SLOTS * FSTRIDE];
    __shared__ __align__(16) unsigned dx_lds32[4 * 512];
    __shared__ int slot_src[SLOTS], slot_dst[SLOTS], slot_side[SLOTS], slot_e[SLOTS];

    const int n    = blockIdx.x;
    const int tid  = threadIdx.x;
    const int lane = tid & 63;
    const int wv   = tid >> 6;
    const int use64 = (*flag == 0);

    const unsigned start = off[n];
    const int deg = (int)(off[n + 1] - start);

    const int r31 = lane & 31;
    const int hi  = lane >> 5;
    const int kb  = hi * 8;
    unsigned* dx2 = dx_lds32 + wv * 512;

    f32x16 acc;
#pragma unroll
    for (int r = 0; r < 16; ++r) acc[r] = 0.f;

    for (int base = 0; base < deg; base += SLOTS) {
        __syncthreads();
        if (tid < SLOTS) {
            int p = base + tid;
            if (p < deg) {
                unsigned v = inc[start + p];
                int e = (int)(v & 0x7fffffffu);
                int s, d; decode_edge(eidx_raw, use64, e, s, d);
                if ((unsigned)s >= NN) s = 0;
                if ((unsigned)d >= NN) d = 0;
                slot_e[tid] = e; slot_src[tid] = s; slot_dst[tid] = d;
                slot_side[tid] = (int)(v >> 31);
            } else slot_e[tid] = -1;
        }
        __syncthreads();

        bf16x8 pre0[4], pre1[4], pre2[4], pre3[4];
        if constexpr (XT) {
#pragma unroll
            for (int s = 0; s < 4; ++s) {
                const int si = wv + 4 * s;
                if (base + si < deg) {
                    const unsigned short* xls = xTbuf + (size_t)slot_src[si] * 2048 + r31 * 32 + kb;
                    const unsigned short* xrs = xTbuf + (size_t)slot_dst[si] * 2048 + r31 * 32 + kb;
                    pre0[s] = *(const bf16x8*)xls;
                    pre1[s] = *(const bf16x8*)(xls + 16);
                    pre2[s] = *(const bf16x8*)xrs;
                    pre3[s] = *(const bf16x8*)(xrs + 16);
                }
            }
        }

        {
            const int slot = lane & 15;
            const int ab   = (lane >> 4) * 8;
            const int e    = slot_e[slot];
            bf16x8 bfrag = {0, 0, 0, 0, 0, 0, 0, 0};
            if (e >= 0) {
                const float* eap = ea + (size_t)e * 32 + ab;
                f32x4 a0 = *(const f32x4*)eap;
                f32x4 a1 = *(const f32x4*)(eap + 4);
#pragma unroll
                for (int j = 0; j < 4; ++j) { bfrag[j] = (short)f2bf(a0[j]); bfrag[4 + j] = (short)f2bf(a1[j]); }
            }
            unsigned short* fdst = F_lds + slot * FSTRIDE;
            const int pg = (lane >> 4) * 4;
#pragma unroll 8
            for (int t = 0; t < 32; ++t) {
                const int pos_base = wv * 512 + t * 16;
                bf16x8 afrag = *(const bf16x8*)(RbfT + (size_t)(pos_base + (lane & 15)) * 32 + ab);
                f32x4 c = {0.f, 0.f, 0.f, 0.f};
                c = __builtin_amdgcn_mfma_f32_16x16x32_bf16(afrag, bfrag, c, 0, 0, 0);
                const int posb = pos_base + pg;
                const int side = posb >> 10;
                const int ijb  = posb & 1023;
                const int i    = ijb >> 5;
                const int soff = ijb ^ ((i & 7) << 3);
                uint2v wp = {pack2bf(c[0], c[1]), pack2bf(c[2], c[3])};
                *(uint2v*)(fdst + side * 1024 + soff) = wp;
            }
        }
        __syncthreads();

#pragma unroll
        for (int s = 0; s < 4; ++s) {
            const int si = wv + 4 * s;
            if (base + si >= deg) break;
            const int src  = slot_src[si];
            const int dst  = slot_dst[si];
            const int side = slot_side[si];

            bf16x8 xlf0, xlf1, xrf0, xrf1;
            if constexpr (XT) {
                xlf0 = pre0[s];
                xlf1 = pre1[s];
                xrf0 = bneg8(pre2[s]);
                xrf1 = bneg8(pre3[s]);
            } else {
                const float* xl = x + (size_t)src * 1024 + r31;
                const float* xr = x + (size_t)dst * 1024 + r31;
#pragma unroll
                for (int j = 0; j < 8; ++j) {
                    xlf0[j] = (short)f2bf(xl[(kb + j) * 32]);
                    xlf1[j] = (short)f2bf(xl[(16 + kb + j) * 32]);
                    xrf0[j] = (short)f2bf(-xr[(kb + j) * 32]);
                    xrf1[j] = (short)f2bf(-xr[(16 + kb + j) * 32]);
                }
            }

            const unsigned short* Fl = F_lds + si * FSTRIDE;
            const unsigned short* Fr = Fl + 1024;
            const int rbase = r31 * 32;
            const int rsw   = (r31 & 7) << 3;
            bf16x8 fl0 = *(const bf16x8*)(Fl + ((rbase + kb) ^ rsw));
            bf16x8 fl1 = *(const bf16x8*)(Fl + ((rbase + 16 + kb) ^ rsw));
            bf16x8 fr0 = *(const bf16x8*)(Fr + ((rbase + kb) ^ rsw));
            bf16x8 fr1 = *(const bf16x8*)(Fr + ((rbase + 16 + kb) ^ rsw));

            f32x16 dacc;
#pragma unroll
            for (int r = 0; r < 16; ++r) dacc[r] = 0.f;
            dacc = __builtin_amdgcn_mfma_f32_32x32x16_bf16(fl0, xlf0, dacc, 0, 0, 0);
            dacc = __builtin_amdgcn_mfma_f32_32x32x16_bf16(fl1, xlf1, dacc, 0, 0, 0);
            dacc = __builtin_amdgcn_mfma_f32_32x32x16_bf16(fr0, xrf0, dacc, 0, 0, 0);
            dacc = __builtin_amdgcn_mfma_f32_32x32x16_bf16(fr1, xrf1, dacc, 0, 0, 0);

            const unsigned smask = side ? 0x80008000u : 0u;
#pragma unroll
            for (int m = 0; m < 8; ++m) {
                const int wi = (m & 1) + 4 * (m >> 1) + 2 * hi;
                dx2[wi * 32 + r31] = pack2bf(dacc[2 * m], dacc[2 * m + 1]) ^ smask;
            }
            unsigned wa[4], wb[4];
#pragma unroll
            for (int m = 0; m < 4; ++m) {
                wa[m] = dx2[(4 * hi + m) * 32 + r31];
                wb[m] = dx2[(8 + 4 * hi + m) * 32 + r31];
            }
            union { uint4v u; bf16x8 s; } pa, pb;
            pa.u = (uint4v){wa[0], wa[1], wa[2], wa[3]};
            pb.u = (uint4v){wb[0], wb[1], wb[2], wb[3]};
            const bf16x8 dxf0 = pa.s, dxf1 = pb.s;

            const unsigned short* Fs = side ? Fr : Fl;
            bf16x8 fT0, fT1;
#pragma unroll
            for (int j = 0; j < 8; ++j) {
                const int k0 = kb + j, k1 = 16 + kb + j;
                fT0[j] = (short)Fs[(k0 * 32 + r31) ^ ((k0 & 7) << 3)];
                fT1[j] = (short)Fs[(k1 * 32 + r31) ^ ((k1 & 7) << 3)];
            }
            acc = __builtin_amdgcn_mfma_f32_32x32x16_bf16(fT0, dxf0, acc, 0, 0, 0);
            acc = __builtin_amdgcn_mfma_f32_32x32x16_bf16(fT1, dxf1, acc, 0, 0, 0);
        }
    }

    __syncthreads();
    float* red = (float*)F_lds;
#pragma unroll
    for (int r = 0; r < 16; ++r) {
        const int row = (r & 3) + 8 * (r >> 2) + 4 * hi;
        red[wv * 1024 + row * 32 + r31] = acc[r];
    }
    __syncthreads();
    {
        const int p4 = tid * 4;
        f32x4 s0 = *(const f32x4*)(red + p4);
        f32x4 s1 = *(const f32x4*)(red + 1024 + p4);
        f32x4 s2 = *(const f32x4*)(red + 2048 + p4);
        f32x4 s3 = *(const f32x4*)(red + 3072 + p4);
        f32x4 o;
#pragma unroll
        for (int j = 0; j < 4; ++j) o[j] = (s0[j] + s1[j]) + (s2[j] + s3[j]);
        *(f32x4*)(out + (size_t)n * 1024 + p4) = o;
    }
}

// ---- Fallback: proven atomic kernel (only if ws < CSR needs) ----
__global__ __launch_bounds__(512, 4) void sheaf_atomic(
    const float* __restrict__ x,
    const void* __restrict__ eidx_raw,
    const float* __restrict__ ea,
    const unsigned short* __restrict__ RbfT,
    const int* __restrict__ flag,
    float* __restrict__ out)
{
    __shared__ __align__(16) unsigned short F_lds[16 * 2048];
    __shared__ __align__(16) unsigned short dx_lds[8 * 1024];

    const int tid  = threadIdx.x;
    const int lane = tid & 63;
    const int wv   = tid >> 6;
    const int e0   = blockIdx.x * 16;
    const int use64 = (*flag == 0);

    {
        const int arow = lane & 15;
        const int ab   = (lane >> 4) * 8;
        const float* eap = ea + (size_t)(e0 + arow) * 32 + ab;
        f32x4 a0 = *(const f32x4*)eap;
        f32x4 a1 = *(const f32x4*)(eap + 4);
        bf16x8 afrag;
#pragma unroll
        for (int j = 0; j < 4; ++j) { afrag[j] = (short)f2bf(a0[j]); afrag[4 + j] = (short)f2bf(a1[j]); }
        const int pcol  = lane & 15;
        const int ebase = (lane >> 4) * 4;
#pragma unroll
        for (int t = 0; t < 16; ++t) {
            const int pos = wv * 256 + t * 16 + pcol;
            bf16x8 bfrag = *(const bf16x8*)(RbfT + pos * 32 + ab);
            f32x4 c = {0.f, 0.f, 0.f, 0.f};
            c = __builtin_amdgcn_mfma_f32_16x16x32_bf16(afrag, bfrag, c, 0, 0, 0);
            const int side = pos >> 10;
            const int ij   = pos & 1023;
            const int i    = ij >> 5;
            const int soff = side * 1024 + (ij ^ ((i & 7) << 3));
#pragma unroll
            for (int r = 0; r < 4; ++r)
                F_lds[(ebase + r) * 2048 + soff] = f2bf(c[r]);
        }
    }
    __syncthreads();

    const int r31 = lane & 31;
    const int hi  = lane >> 5;
    const int kb  = hi * 8;
    unsigned short* dxb = dx_lds + wv * 1024;

#pragma unroll 1
    for (int sub = 0; sub < 2; ++sub) {
        const int el = wv * 2 + sub;
        const int e  = e0 + el;
        int src, dst;
        decode_edge(eidx_raw, use64, e, src, dst);
        if ((unsigned)src >= NN || (unsigned)dst >= NN) continue;

        const float* xl = x + (size_t)src * 1024 + r31;
        const float* xr = x + (size_t)dst * 1024 + r31;
        bf16x8 xlf0, xlf1, xrf0, xrf1;
#pragma unroll
        for (int j = 0; j < 8; ++j) {
            xlf0[j] = (short)f2bf(xl[(kb + j) * 32]);
            xlf1[j] = (short)f2bf(xl[(16 + kb + j) * 32]);
            xrf0[j] = (short)f2bf(-xr[(kb + j) * 32]);
            xrf1[j] = (short)f2bf(-xr[(16 + kb + j) * 32]);
        }
        const unsigned short* Fl = F_lds + el * 2048;
        const unsigned short* Fr = Fl + 1024;
        const int rbase = r31 * 32;
        const int rsw   = (r31 & 7) << 3;
        bf16x8 fl0 = *(const bf16x8*)(Fl + ((rbase + kb) ^ rsw));
        bf16x8 fl1 = *(const bf16x8*)(Fl + ((rbase + 16 + kb) ^ rsw));
        bf16x8 fr0 = *(const bf16x8*)(Fr + ((rbase + kb) ^ rsw));
        bf16x8 fr1 = *(const bf16x8*)(Fr + ((rbase + 16 + kb) ^ rsw));

        f32x16 dacc;
#pragma unroll
        for (int r = 0; r < 16; ++r) dacc[r] = 0.f;
        dacc = __builtin_amdgcn_mfma_f32_32x32x16_bf16(fl0, xlf0, dacc, 0, 0, 0);
        dacc = __builtin_amdgcn_mfma_f32_32x32x16_bf16(fl1, xlf1, dacc, 0, 0, 0);
        dacc = __builtin_amdgcn_mfma_f32_32x32x16_bf16(fr0, xrf0, dacc, 0, 0, 0);
        dacc = __builtin_amdgcn_mfma_f32_32x32x16_bf16(fr1, xrf1, dacc, 0, 0, 0);

#pragma unroll
        for (int r = 0; r < 16; ++r) {
            const int row = (r & 3) + 8 * (r >> 2) + 4 * hi;
            dxb[row * 32 + r31] = f2bf(dacc[r]);
        }
        bf16x8 dxf0, dxf1;
#pragma unroll
        for (int j = 0; j < 8; ++j) {
            dxf0[j] = (short)dxb[(kb + j) * 32 + r31];
            dxf1[j] = (short)dxb[(16 + kb + j) * 32 + r31];
        }

        bf16x8 flT0, flT1;
#pragma unroll
        for (int j = 0; j < 8; ++j) {
            const int k0 = kb + j, k1 = 16 + kb + j;
            flT0[j] = (short)Fl[(k0 * 32 + r31) ^ ((k0 & 7) << 3)];
            flT1[j] = (short)Fl[(k1 * 32 + r31) ^ ((k1 & 7) << 3)];
        }
        f32x16 yl;
#pragma unroll
        for (int r = 0; r < 16; ++r) yl[r] = 0.f;
        yl = __builtin_amdgcn_mfma_f32_32x32x16_bf16(flT0, dxf0, yl, 0, 0, 0);
        yl = __builtin_amdgcn_mfma_f32_32x32x16_bf16(flT1, dxf1, yl, 0, 0, 0);
        float* outs = out + (size_t)src * 1024 + r31;
#pragma unroll
        for (int r = 0; r < 16; ++r) {
            const int row = (r & 3) + 8 * (r >> 2) + 4 * hi;
            atomicAdd(outs + row * 32, yl[r]);
        }

        bf16x8 frT0, frT1;
#pragma unroll
        for (int j = 0; j < 8; ++j) {
            const int k0 = kb + j, k1 = 16 + kb + j;
            frT0[j] = (short)Fr[(k0 * 32 + r31) ^ ((k0 & 7) << 3)];
            frT1[j] = (short)Fr[(k1 * 32 + r31) ^ ((k1 & 7) << 3)];
        }
        f32x16 yr;
#pragma unroll
        for (int r = 0; r < 16; ++r) yr[r] = 0.f;
        yr = __builtin_amdgcn_mfma_f32_32x32x16_bf16(frT0, dxf0, yr, 0, 0, 0);
        yr = __builtin_amdgcn_mfma_f32_32x32x16_bf16(frT1, dxf1, yr, 0, 0, 0);
        float* outd = out + (size_t)dst * 1024 + r31;
#pragma unroll
        for (int r = 0; r < 16; ++r) {
            const int row = (r & 3) + 8 * (r >> 2) + 4 * hi;
            atomicAdd(outd + row * 32, -yr[r]);
        }
    }
}

extern "C" void kernel_launch(void* const* d_in, const int* in_sizes, int n_in,
                              void* d_out, int out_size, void* d_ws, size_t ws_size,
                              hipStream_t stream) {
    const float* x  = (const float*)d_in[0];
    const void* eidx = d_in[1];
    const float* ea = (const float*)d_in[2];
    const float* R  = (const float*)d_in[3];
    float* out = (float*)d_out;
    char* ws = (char*)d_ws;

    unsigned short* RbfT = (unsigned short*)(ws + WS_RBFT);
    int* flag = (int*)(ws + WS_FLAG);

    prep_rbf_kernel<<<256, 256, 0, stream>>>(R, RbfT, flag);
    detect_kernel<<<(NE + 255) / 256, 256, 0, stream>>>((const unsigned*)eidx, flag);

    if (ws_size >= WS_CSR_END) {
        unsigned* off = (unsigned*)(ws + WS_OFF);
        unsigned* cur = (unsigned*)(ws + WS_CUR);
        unsigned* cnt = (unsigned*)(ws + WS_CNT);
        unsigned* inc = (unsigned*)(ws + WS_INC);
        unsigned* nodeOf = (unsigned*)(ws + WS_NODE);

        hipMemsetAsync(cnt, 0, 4u * NN, stream);
        count_kernel<<<(NE + 255) / 256, 256, 0, stream>>>(eidx, flag, cnt);
        scan_kernel<<<1, 1024, 0, stream>>>(cnt, off, cur);
        scatter_kernel<<<(NE + 255) / 256, 256, 0, stream>>>(eidx, flag, cur, inc, nodeOf);

        if (ws_size >= WS_PB_END) {
            unsigned short* xT = (unsigned short*)(ws + WS_XT);
            unsigned short* pbuf = (unsigned short*)(ws + WS_PB);
            xpose_kernel<<<NN / 4, 256, 0, stream>>>(x, xT);
            sheaf_inc<<<NB, 256, 0, stream>>>(xT, eidx, ea, RbfT, flag, off, inc, nodeOf, out, pbuf);
            combine_kernel<<<NN, 256, 0, stream>>>(off, nodeOf, pbuf, out);
        } else if (ws_size >= WS_XT_END) {
            unsigned short* xT = (unsigned short*)(ws + WS_XT);
            xpose_kernel<<<NN / 4, 256, 0, stream>>>(x, xT);
            sheaf_node<true><<<NN, 256, 0, stream>>>(x, xT, eidx, ea, RbfT, flag, off, inc, out);
        } else {
            sheaf_node<false><<<NN, 256, 0, stream>>>(x, nullptr, eidx, ea, RbfT, flag, off, inc, out);
        }
    } else {
        hipMemsetAsync(d_out, 0, (size_t)out_size * sizeof(float), stream);
        sheaf_atomic<<<NE / 16, 512, 0, stream>>>(x, eidx, ea, RbfT, flag, out);
    }
}

// Round 14
// 346.324 us; speedup vs baseline: 1.2491x; 1.2491x over previous
//
#include <hip/hip_runtime.h>
#include <hip/hip_bf16.h>

#define NN 20000
#define NE 100000
#define NINC (2 * NE)        // 200000 incidences
#define NB (NINC / 16)       // 12500 incidence batches, exactly full
#define PGRID 512            // persistent blocks (2/CU)
#define SLOTS 16
#define FSTRIDE 2056   // u16 per slot: 2048 + 8 pad -> slot base advances 4 banks

typedef __attribute__((ext_vector_type(8))) short bf16x8;
typedef __attribute__((ext_vector_type(4))) float f32x4;
typedef __attribute__((ext_vector_type(16))) float f32x16;
typedef __attribute__((ext_vector_type(2))) unsigned uint2v;
typedef __attribute__((ext_vector_type(4))) unsigned uint4v;

// ---- ws layout ----
#define WS_RBFT 0u
#define WS_FLAG 131072u
#define WS_OFF  131328u                          // uint off[NN+1]
#define WS_CUR  (WS_OFF + 4u*(NN+1))             // uint cur[NN]
#define WS_CNT  (WS_CUR + 4u*NN)                 // uint cnt[NN]
#define WS_INC  (WS_CNT + 4u*NN)                 // uint inc[2*NE]
#define WS_NODE (WS_INC + 4u*NINC)               // uint nodeOf[2*NE]
#define WS_CSR_END ((size_t)WS_NODE + 4u*NINC)
#define WS_XT   ((WS_CSR_END + 4095u) & ~(size_t)4095u)
#define WS_XT_END (WS_XT + (size_t)NN * 2048u * 2u)   // bf16 xT[n][f][k]
#define WS_PB   ((WS_XT_END + 4095u) & ~(size_t)4095u)
#define WS_PB_END (WS_PB + (size_t)NB * 2u * 2048u)   // bf16 pbuf[NB][2][1024]

__device__ __forceinline__ unsigned short f2bf(float f) {
    unsigned u = __float_as_uint(f);
    u += 0x7fffu + ((u >> 16) & 1u);
    return (unsigned short)(u >> 16);
}

__device__ __forceinline__ unsigned pack2bf(float a, float b) {
    union { __hip_bfloat162 h; unsigned u; } q;
    q.h = __float22bfloat162_rn(make_float2(a, b));
    return q.u;
}

__device__ __forceinline__ float bf2f(unsigned s) {
    return __uint_as_float(s << 16);
}

__device__ __forceinline__ bf16x8 bneg8(bf16x8 v) {
    union { bf16x8 s; uint4v u; } a; a.s = v;
    a.u[0] ^= 0x80008000u; a.u[1] ^= 0x80008000u;
    a.u[2] ^= 0x80008000u; a.u[3] ^= 0x80008000u;
    return a.s;
}

// RbfT bf16 [pos(2048)][a(32)]; zero the int64-detect flag
__global__ void prep_rbf_kernel(const float* __restrict__ R, unsigned short* __restrict__ RbfT,
                                int* __restrict__ flag) {
    int idx = blockIdx.x * blockDim.x + threadIdx.x;
    if (idx == 0) *flag = 0;
    if (idx >= 2048 * 32) return;
    int pos = idx >> 5;
    int a = idx & 31;
    RbfT[idx] = f2bf(R[a * 2048 + pos]);
}

__global__ void detect_kernel(const unsigned* __restrict__ w, int* __restrict__ flag) {
    int k = blockIdx.x * blockDim.x + threadIdx.x;
    if (k < NE && w[2 * k + 1] != 0) atomicOr(flag, 1);
}

__device__ __forceinline__ void decode_edge(const void* eidx, int use64, int e, int& src, int& dst) {
    if (use64) {
        const long long* p = (const long long*)eidx;
        src = (int)p[e]; dst = (int)p[NE + e];
    } else {
        const int* p = (const int*)eidx;
        src = p[e]; dst = p[NE + e];
    }
}

__global__ void count_kernel(const void* __restrict__ eidx, const int* __restrict__ flag,
                             unsigned* __restrict__ cnt) {
    int e = blockIdx.x * blockDim.x + threadIdx.x;
    if (e >= NE) return;
    int src, dst;
    decode_edge(eidx, *flag == 0, e, src, dst);
    if ((unsigned)src < NN) atomicAdd(&cnt[src], 1u);
    if ((unsigned)dst < NN) atomicAdd(&cnt[dst], 1u);
}

__global__ __launch_bounds__(1024) void scan_kernel(const unsigned* __restrict__ cnt,
                                                    unsigned* __restrict__ off,
                                                    unsigned* __restrict__ cur) {
    __shared__ unsigned sd[1024];
    const int t = threadIdx.x;
    unsigned vals[20];
    unsigned s = 0;
#pragma unroll
    for (int j = 0; j < 20; ++j) {
        int idx = t * 20 + j;
        unsigned v = (idx < NN) ? cnt[idx] : 0u;
        vals[j] = s; s += v;
    }
    sd[t] = s;
    __syncthreads();
    for (int d = 1; d < 1024; d <<= 1) {
        unsigned v = (t >= d) ? sd[t - d] : 0u;
        __syncthreads();
        sd[t] += v;
        __syncthreads();
    }
    unsigned base = (t > 0) ? sd[t - 1] : 0u;
#pragma unroll
    for (int j = 0; j < 20; ++j) {
        int idx = t * 20 + j;
        if (idx < NN) { unsigned o = base + vals[j]; off[idx] = o; cur[idx] = o; }
    }
    if (t == 1023) off[NN] = sd[1023];
}

__global__ void scatter_kernel(const void* __restrict__ eidx, const int* __restrict__ flag,
                               unsigned* __restrict__ cur, unsigned* __restrict__ inc,
                               unsigned* __restrict__ nodeOf) {
    int e = blockIdx.x * blockDim.x + threadIdx.x;
    if (e >= NE) return;
    int src, dst;
    decode_edge(eidx, *flag == 0, e, src, dst);
    if ((unsigned)src < NN) { unsigned p = atomicAdd(&cur[src], 1u); inc[p] = (unsigned)e; nodeOf[p] = (unsigned)src; }
    if ((unsigned)dst < NN) { unsigned p = atomicAdd(&cur[dst], 1u); inc[p] = (unsigned)e | 0x80000000u; nodeOf[p] = (unsigned)dst; }
}

// ---- transpose+convert: xT[n][f][k] bf16 from x[n][k][f] f32 (4 nodes/block) ----
__global__ __launch_bounds__(256) void xpose_kernel(const float* __restrict__ x,
                                                    unsigned short* __restrict__ xT) {
    __shared__ float tile[4][32][33];
    const int t = threadIdx.x, sub = t >> 6, lane = t & 63;
    const int n = blockIdx.x * 4 + sub;
    const int row = lane >> 1, half = (lane & 1) * 16;
    const float* xp = x + (size_t)n * 1024 + row * 32 + half;
    float* tp = &tile[sub][row][half];
#pragma unroll
    for (int c = 0; c < 4; ++c)
        *(f32x4*)(tp + 4 * c) = *(const f32x4*)(xp + 4 * c);
    __syncthreads();
    const int f = lane >> 1, k0 = (lane & 1) * 16;
    unsigned w[8];
#pragma unroll
    for (int m = 0; m < 8; ++m) {
        unsigned lo = (unsigned)f2bf(tile[sub][k0 + 2 * m][f]);
        unsigned hi = (unsigned)f2bf(tile[sub][k0 + 2 * m + 1][f]);
        w[m] = lo | (hi << 16);
    }
    unsigned short* op = xT + (size_t)n * 2048 + f * 32 + k0;
    uint4v v0 = {w[0], w[1], w[2], w[3]};
    uint4v v1 = {w[4], w[5], w[6], w[7]};
    *(uint4v*)op = v0;
    *(uint4v*)(op + 8) = v1;
}

// ---- Persistent incidence-batch kernel: 512 blocks grid-stride over 12500 batches.
// RbfT A-fragments (this wave's 512-position range) held in 128 VGPRs for the whole
// kernel -> phase A is register-operand MFMA only. Body otherwise identical to the
// proven R12 sheaf_inc (slot-fill stage, T14 prefetch, dx-in-LDS-rowpair, segsum).
__global__ __launch_bounds__(256, 2) void sheaf_inc(
    const unsigned short* __restrict__ xTbuf,
    const void* __restrict__ eidx_raw,
    const float* __restrict__ ea,
    const unsigned short* __restrict__ RbfT,
    const int* __restrict__ flag,
    const unsigned* __restrict__ off,
    const unsigned* __restrict__ inc,
    const unsigned* __restrict__ nodeOf,
    float* __restrict__ out,
    unsigned short* __restrict__ pbuf)
{
    __shared__ __align__(16) unsigned short F_lds[SLOTS * FSTRIDE]; // 64.25KB; F then per-slot y (f32)
    __shared__ __align__(16) unsigned dx_lds32[4 * 512];            // per-wave [rowpair(16)][col(32)] u32
    __shared__ int slot_src[SLOTS], slot_dst[SLOTS], slot_side[SLOTS], slot_e[SLOTS], slot_n[SLOTS];

    const int tid  = threadIdx.x;
    const int lane = tid & 63;
    const int wv   = tid >> 6;
    const int use64 = (*flag == 0);

    const int r31 = lane & 31;
    const int hi  = lane >> 5;
    const int kb  = hi * 8;
    const int l15 = lane & 15;
    const int ab  = (lane >> 4) * 8;
    const int pg  = (lane >> 4) * 4;
    unsigned* dx2 = dx_lds32 + wv * 512;

    // ---- persistent: this wave's 32 RbfT A-fragments (128 VGPR), loaded once ----
    bf16x8 rbft[32];
#pragma unroll
    for (int t = 0; t < 32; ++t)
        rbft[t] = *(const bf16x8*)(RbfT + (size_t)(wv * 512 + t * 16 + l15) * 32 + ab);

    for (int b = blockIdx.x; b < NB; b += PGRID) {
        const int p0 = b * 16;
        __syncthreads();   // previous batch's segsum done before overwriting F_lds/slot arrays

        // ---- slot fill (all 16 valid: NINC is a multiple of 16) ----
        if (tid < SLOTS) {
            unsigned v = inc[p0 + tid];
            int e = (int)(v & 0x7fffffffu);
            int s, d; decode_edge(eidx_raw, use64, e, s, d);
            if ((unsigned)s >= NN) s = 0;
            if ((unsigned)d >= NN) d = 0;
            slot_e[tid] = e; slot_src[tid] = s; slot_dst[tid] = d;
            slot_side[tid] = (int)(v >> 31);
            slot_n[tid] = (int)nodeOf[p0 + tid];
        }
        __syncthreads();

        // ---- T14 prefetch: this wave's 4 slots' xT gathers ----
        bf16x8 pre0[4], pre1[4], pre2[4], pre3[4];
#pragma unroll
        for (int s = 0; s < 4; ++s) {
            const int si = wv + 4 * s;
            const unsigned short* xls = xTbuf + (size_t)slot_src[si] * 2048 + r31 * 32 + kb;
            const unsigned short* xrs = xTbuf + (size_t)slot_dst[si] * 2048 + r31 * 32 + kb;
            pre0[s] = *(const bf16x8*)xls;
            pre1[s] = *(const bf16x8*)(xls + 16);
            pre2[s] = *(const bf16x8*)xrs;
            pre3[s] = *(const bf16x8*)(xrs + 16);
        }

        // ---- Phase A (operand-swapped, register A-operands): F[slot][pos] ----
        {
            const int e = slot_e[l15];
            bf16x8 bfrag;
            {
                const float* eap = ea + (size_t)e * 32 + ab;
                f32x4 a0 = *(const f32x4*)eap;
                f32x4 a1 = *(const f32x4*)(eap + 4);
#pragma unroll
                for (int j = 0; j < 4; ++j) { bfrag[j] = (short)f2bf(a0[j]); bfrag[4 + j] = (short)f2bf(a1[j]); }
            }
            unsigned short* fdst = F_lds + l15 * FSTRIDE;
#pragma unroll
            for (int t = 0; t < 32; ++t) {
                f32x4 c = {0.f, 0.f, 0.f, 0.f};
                c = __builtin_amdgcn_mfma_f32_16x16x32_bf16(rbft[t], bfrag, c, 0, 0, 0);
                const int posb = wv * 512 + t * 16 + pg;   // 4-aligned
                const int side = posb >> 10;
                const int ijb  = posb & 1023;
                const int i    = ijb >> 5;
                const int soff = ijb ^ ((i & 7) << 3);     // XOR bits 3-5; 4-chunk stays contiguous
                uint2v wp = {pack2bf(c[0], c[1]), pack2bf(c[2], c[3])};
                *(uint2v*)(fdst + side * 1024 + soff) = wp;
            }
        }
        __syncthreads();

        // ---- Phase B: wave wv handles slots wv, wv+4, wv+8, wv+12; y -> F_lds[si] (f32) ----
#pragma unroll
        for (int s = 0; s < 4; ++s) {
            const int si = wv + 4 * s;
            const int side = slot_side[si];

            bf16x8 xlf0 = pre0[s];
            bf16x8 xlf1 = pre1[s];
            bf16x8 xrf0 = bneg8(pre2[s]);
            bf16x8 xrf1 = bneg8(pre3[s]);

            const unsigned short* Fl = F_lds + si * FSTRIDE;
            const unsigned short* Fr = Fl + 1024;
            const int rbase = r31 * 32;
            const int rsw   = (r31 & 7) << 3;
            bf16x8 fl0 = *(const bf16x8*)(Fl + ((rbase + kb) ^ rsw));
            bf16x8 fl1 = *(const bf16x8*)(Fl + ((rbase + 16 + kb) ^ rsw));
            bf16x8 fr0 = *(const bf16x8*)(Fr + ((rbase + kb) ^ rsw));
            bf16x8 fr1 = *(const bf16x8*)(Fr + ((rbase + 16 + kb) ^ rsw));

            f32x16 dacc;
#pragma unroll
            for (int r = 0; r < 16; ++r) dacc[r] = 0.f;
            dacc = __builtin_amdgcn_mfma_f32_32x32x16_bf16(fl0, xlf0, dacc, 0, 0, 0);
            dacc = __builtin_amdgcn_mfma_f32_32x32x16_bf16(fl1, xlf1, dacc, 0, 0, 0);
            dacc = __builtin_amdgcn_mfma_f32_32x32x16_bf16(fr0, xrf0, dacc, 0, 0, 0);
            dacc = __builtin_amdgcn_mfma_f32_32x32x16_bf16(fr1, xrf1, dacc, 0, 0, 0);

            // dx -> LDS row-pair packed (sign via uniform XOR), read back as B-fragment
            const unsigned smask = side ? 0x80008000u : 0u;
#pragma unroll
            for (int m = 0; m < 8; ++m) {
                const int wi = (m & 1) + 4 * (m >> 1) + 2 * hi;   // rowpair index
                dx2[wi * 32 + r31] = pack2bf(dacc[2 * m], dacc[2 * m + 1]) ^ smask;
            }
            unsigned wa[4], wb[4];
#pragma unroll
            for (int m = 0; m < 4; ++m) {
                wa[m] = dx2[(4 * hi + m) * 32 + r31];
                wb[m] = dx2[(8 + 4 * hi + m) * 32 + r31];
            }
            union { uint4v u; bf16x8 s; } pa, pb;
            pa.u = (uint4v){wa[0], wa[1], wa[2], wa[3]};
            pb.u = (uint4v){wb[0], wb[1], wb[2], wb[3]};
            const bf16x8 dxf0 = pa.s, dxf1 = pb.s;

            // y = F_side^T (sgn*dx)
            const unsigned short* Fs = side ? Fr : Fl;
            bf16x8 fT0, fT1;
#pragma unroll
            for (int j = 0; j < 8; ++j) {
                const int k0 = kb + j, k1 = 16 + kb + j;
                fT0[j] = (short)Fs[(k0 * 32 + r31) ^ ((k0 & 7) << 3)];
                fT1[j] = (short)Fs[(k1 * 32 + r31) ^ ((k1 & 7) << 3)];
            }
            f32x16 y;
#pragma unroll
            for (int r = 0; r < 16; ++r) y[r] = 0.f;
            y = __builtin_amdgcn_mfma_f32_32x32x16_bf16(fT0, dxf0, y, 0, 0, 0);
            y = __builtin_amdgcn_mfma_f32_32x32x16_bf16(fT1, dxf1, y, 0, 0, 0);

            // write y over the (now dead) F slot, f32 [32][32]; same-wave ordering only
            float* ybuf = (float*)(F_lds + si * FSTRIDE);
#pragma unroll
            for (int r = 0; r < 16; ++r) {
                const int row = (r & 3) + 8 * (r >> 2) + 4 * hi;
                ybuf[row * 32 + r31] = y[r];
            }
        }
        __syncthreads();

        // ---- segmented sum over slots (runs of equal slot_n); each thread owns 4 elems ----
        {
            const int e4 = tid * 4;
            int segA = 0;
            while (segA < SLOTS) {
                const int n = slot_n[segA];
                int segB = segA + 1;
                while (segB < SLOTS && slot_n[segB] == n) ++segB;
                f32x4 sum = {0.f, 0.f, 0.f, 0.f};
                for (int s2 = segA; s2 < segB; ++s2) {
                    const f32x4 v = *(const f32x4*)((const float*)(F_lds + s2 * FSTRIDE) + e4);
#pragma unroll
                    for (int j = 0; j < 4; ++j) sum[j] += v[j];
                }
                const unsigned on = off[n], on1 = off[n + 1];
                const bool complete = ((unsigned)(p0 + segA) == on) && ((unsigned)(p0 + segB) == on1);
                if (complete) {
                    *(f32x4*)(out + (size_t)n * 1024 + e4) = sum;
                } else {
                    const int idx = (segA == 0) ? 0 : 1;
                    unsigned short* pb = pbuf + ((size_t)b * 2 + idx) * 1024;
                    uint2v wp = {pack2bf(sum[0], sum[1]), pack2bf(sum[2], sum[3])};
                    *(uint2v*)(pb + e4) = wp;
                }
                segA = segB;
            }
        }
    }
}

// ---- epilogue: combine boundary partials; zero deg-0 nodes ----
__global__ __launch_bounds__(256) void combine_kernel(
    const unsigned* __restrict__ off, const unsigned* __restrict__ nodeOf,
    const unsigned short* __restrict__ pbuf, float* __restrict__ out)
{
    const int n = blockIdx.x;
    const int e4 = threadIdx.x * 4;
    const unsigned a = off[n], b = off[n + 1];
    if (a == b) {
        f32x4 z = {0.f, 0.f, 0.f, 0.f};
        *(f32x4*)(out + (size_t)n * 1024 + e4) = z;
        return;
    }
    const unsigned b0 = a >> 4, b1 = (b - 1) >> 4;
    if (b0 == b1) return;   // complete segment; main kernel wrote it
    f32x4 sum = {0.f, 0.f, 0.f, 0.f};
    for (unsigned blk = b0; blk <= b1; ++blk) {
        const int idx = (nodeOf[blk * 16] == (unsigned)n) ? 0 : 1;
        const unsigned short* pb = pbuf + ((size_t)blk * 2 + idx) * 1024;
        uint2v w = *(const uint2v*)(pb + e4);
        sum[0] += bf2f(w[0] & 0xffffu); sum[1] += bf2f(w[0] >> 16);
        sum[2] += bf2f(w[1] & 0xffffu); sum[3] += bf2f(w[1] >> 16);
    }
    *(f32x4*)(out + (size_t)n * 1024 + e4) = sum;
}

// ---- Fallback: proven R10 node-centric kernel (ws too small for pbuf) ----
template<bool XT>
__global__ __launch_bounds__(256, 2) void sheaf_node(
    const float* __restrict__ x,
    const unsigned short* __restrict__ xTbuf,
    const void* __restrict__ eidx_raw,
    const float* __restrict__ ea,
    const unsigned short* __restrict__ RbfT,
    const int* __restrict__ flag,
    const unsigned* __restrict__ off,
    const unsigned* __restrict__ inc,
    float* __restrict__ out)
{
    __shared__ __align__(16) unsigned short F_lds[SLOTS * FSTRIDE];
    __shared__ __align__(16) unsigned dx_lds32[4 * 512];
    __shared__ int slot_src[SLOTS], slot_dst[SLOTS], slot_side[SLOTS], slot_e[SLOTS];

    const int n    = blockIdx.x;
    const int tid  = threadIdx.x;
    const int lane = tid & 63;
    const int wv   = tid >> 6;
    const int use64 = (*flag == 0);

    const unsigned start = off[n];
    const int deg = (int)(off[n + 1] - start);

    const int r31 = lane & 31;
    const int hi  = lane >> 5;
    const int kb  = hi * 8;
    unsigned* dx2 = dx_lds32 + wv * 512;

    f32x16 acc;
#pragma unroll
    for (int r = 0; r < 16; ++r) acc[r] = 0.f;

    for (int base = 0; base < deg; base += SLOTS) {
        __syncthreads();
        if (tid < SLOTS) {
            int p = base + tid;
            if (p < deg) {
                unsigned v = inc[start + p];
                int e = (int)(v & 0x7fffffffu);
                int s, d; decode_edge(eidx_raw, use64, e, s, d);
                if ((unsigned)s >= NN) s = 0;
                if ((unsigned)d >= NN) d = 0;
                slot_e[tid] = e; slot_src[tid] = s; slot_dst[tid] = d;
                slot_side[tid] = (int)(v >> 31);
            } else slot_e[tid] = -1;
        }
        __syncthreads();

        bf16x8 pre0[4], pre1[4], pre2[4], pre3[4];
        if constexpr (XT) {
#pragma unroll
            for (int s = 0; s < 4; ++s) {
                const int si = wv + 4 * s;
                if (base + si < deg) {
                    const unsigned short* xls = xTbuf + (size_t)slot_src[si] * 2048 + r31 * 32 + kb;
                    const unsigned short* xrs = xTbuf + (size_t)slot_dst[si] * 2048 + r31 * 32 + kb;
                    pre0[s] = *(const bf16x8*)xls;
                    pre1[s] = *(const bf16x8*)(xls + 16);
                    pre2[s] = *(const bf16x8*)xrs;
                    pre3[s] = *(const bf16x8*)(xrs + 16);
                }
            }
        }

        {
            const int slot = lane & 15;
            const int ab   = (lane >> 4) * 8;
            const int e    = slot_e[slot];
            bf16x8 bfrag = {0, 0, 0, 0, 0, 0, 0, 0};
            if (e >= 0) {
                const float* eap = ea + (size_t)e * 32 + ab;
                f32x4 a0 = *(const f32x4*)eap;
                f32x4 a1 = *(const f32x4*)(eap + 4);
#pragma unroll
                for (int j = 0; j < 4; ++j) { bfrag[j] = (short)f2bf(a0[j]); bfrag[4 + j] = (short)f2bf(a1[j]); }
            }
            unsigned short* fdst = F_lds + slot * FSTRIDE;
            const int pg = (lane >> 4) * 4;
#pragma unroll 8
            for (int t = 0; t < 32; ++t) {
                const int pos_base = wv * 512 + t * 16;
                bf16x8 afrag = *(const bf16x8*)(RbfT + (size_t)(pos_base + (lane & 15)) * 32 + ab);
                f32x4 c = {0.f, 0.f, 0.f, 0.f};
                c = __builtin_amdgcn_mfma_f32_16x16x32_bf16(afrag, bfrag, c, 0, 0, 0);
                const int posb = pos_base + pg;
                const int side = posb >> 10;
                const int ijb  = posb & 1023;
                const int i    = ijb >> 5;
                const int soff = ijb ^ ((i & 7) << 3);
                uint2v wp = {pack2bf(c[0], c[1]), pack2bf(c[2], c[3])};
                *(uint2v*)(fdst + side * 1024 + soff) = wp;
            }
        }
        __syncthreads();

#pragma unroll
        for (int s = 0; s < 4; ++s) {
            const int si = wv + 4 * s;
            if (base + si >= deg) break;
            const int src  = slot_src[si];
            const int dst  = slot_dst[si];
            const int side = slot_side[si];

            bf16x8 xlf0, xlf1, xrf0, xrf1;
            if constexpr (XT) {
                xlf0 = pre0[s];
                xlf1 = pre1[s];
                xrf0 = bneg8(pre2[s]);
                xrf1 = bneg8(pre3[s]);
            } else {
                const float* xl = x + (size_t)src * 1024 + r31;
                const float* xr = x + (size_t)dst * 1024 + r31;
#pragma unroll
                for (int j = 0; j < 8; ++j) {
                    xlf0[j] = (short)f2bf(xl[(kb + j) * 32]);
                    xlf1[j] = (short)f2bf(xl[(16 + kb + j) * 32]);
                    xrf0[j] = (short)f2bf(-xr[(kb + j) * 32]);
                    xrf1[j] = (short)f2bf(-xr[(16 + kb + j) * 32]);
                }
            }

            const unsigned short* Fl = F_lds + si * FSTRIDE;
            const unsigned short* Fr = Fl + 1024;
            const int rbase = r31 * 32;
            const int rsw   = (r31 & 7) << 3;
            bf16x8 fl0 = *(const bf16x8*)(Fl + ((rbase + kb) ^ rsw));
            bf16x8 fl1 = *(const bf16x8*)(Fl + ((rbase + 16 + kb) ^ rsw));
            bf16x8 fr0 = *(const bf16x8*)(Fr + ((rbase + kb) ^ rsw));
            bf16x8 fr1 = *(const bf16x8*)(Fr + ((rbase + 16 + kb) ^ rsw));

            f32x16 dacc;
#pragma unroll
            for (int r = 0; r < 16; ++r) dacc[r] = 0.f;
            dacc = __builtin_amdgcn_mfma_f32_32x32x16_bf16(fl0, xlf0, dacc, 0, 0, 0);
            dacc = __builtin_amdgcn_mfma_f32_32x32x16_bf16(fl1, xlf1, dacc, 0, 0, 0);
            dacc = __builtin_amdgcn_mfma_f32_32x32x16_bf16(fr0, xrf0, dacc, 0, 0, 0);
            dacc = __builtin_amdgcn_mfma_f32_32x32x16_bf16(fr1, xrf1, dacc, 0, 0, 0);

            const unsigned smask = side ? 0x80008000u : 0u;
#pragma unroll
            for (int m = 0; m < 8; ++m) {
                const int wi = (m & 1) + 4 * (m >> 1) + 2 * hi;
                dx2[wi * 32 + r31] = pack2bf(dacc[2 * m], dacc[2 * m + 1]) ^ smask;
            }
            unsigned wa[4], wb[4];
#pragma unroll
            for (int m = 0; m < 4; ++m) {
                wa[m] = dx2[(4 * hi + m) * 32 + r31];
                wb[m] = dx2[(8 + 4 * hi + m) * 32 + r31];
            }
            union { uint4v u; bf16x8 s; } pa, pb;
            pa.u = (uint4v){wa[0], wa[1], wa[2], wa[3]};
            pb.u = (uint4v){wb[0], wb[1], wb[2], wb[3]};
            const bf16x8 dxf0 = pa.s, dxf1 = pb.s;

            const unsigned short* Fs = side ? Fr : Fl;
            bf16x8 fT0, fT1;
#pragma unroll
            for (int j = 0; j < 8; ++j) {
                const int k0 = kb + j, k1 = 16 + kb + j;
                fT0[j] = (short)Fs[(k0 * 32 + r31) ^ ((k0 & 7) << 3)];
                fT1[j] = (short)Fs[(k1 * 32 + r31) ^ ((k1 & 7) << 3)];
            }
            acc = __builtin_amdgcn_mfma_f32_32x32x16_bf16(fT0, dxf0, acc, 0, 0, 0);
            acc = __builtin_amdgcn_mfma_f32_32x32x16_bf16(fT1, dxf1, acc, 0, 0, 0);
        }
    }

    __syncthreads();
    float* red = (float*)F_lds;
#pragma unroll
    for (int r = 0; r < 16; ++r) {
        const int row = (r & 3) + 8 * (r >> 2) + 4 * hi;
        red[wv * 1024 + row * 32 + r31] = acc[r];
    }
    __syncthreads();
    {
        const int p4 = tid * 4;
        f32x4 s0 = *(const f32x4*)(red + p4);
        f32x4 s1 = *(const f32x4*)(red + 1024 + p4);
        f32x4 s2 = *(const f32x4*)(red + 2048 + p4);
        f32x4 s3 = *(const f32x4*)(red + 3072 + p4);
        f32x4 o;
#pragma unroll
        for (int j = 0; j < 4; ++j) o[j] = (s0[j] + s1[j]) + (s2[j] + s3[j]);
        *(f32x4*)(out + (size_t)n * 1024 + p4) = o;
    }
}

// ---- Fallback: proven atomic kernel (only if ws < CSR needs) ----
__global__ __launch_bounds__(512, 4) void sheaf_atomic(
    const float* __restrict__ x,
    const void* __restrict__ eidx_raw,
    const float* __restrict__ ea,
    const unsigned short* __restrict__ RbfT,
    const int* __restrict__ flag,
    float* __restrict__ out)
{
    __shared__ __align__(16) unsigned short F_lds[16 * 2048];
    __shared__ __align__(16) unsigned short dx_lds[8 * 1024];

    const int tid  = threadIdx.x;
    const int lane = tid & 63;
    const int wv   = tid >> 6;
    const int e0   = blockIdx.x * 16;
    const int use64 = (*flag == 0);

    {
        const int arow = lane & 15;
        const int ab   = (lane >> 4) * 8;
        const float* eap = ea + (size_t)(e0 + arow) * 32 + ab;
        f32x4 a0 = *(const f32x4*)eap;
        f32x4 a1 = *(const f32x4*)(eap + 4);
        bf16x8 afrag;
#pragma unroll
        for (int j = 0; j < 4; ++j) { afrag[j] = (short)f2bf(a0[j]); afrag[4 + j] = (short)f2bf(a1[j]); }
        const int pcol  = lane & 15;
        const int ebase = (lane >> 4) * 4;
#pragma unroll
        for (int t = 0; t < 16; ++t) {
            const int pos = wv * 256 + t * 16 + pcol;
            bf16x8 bfrag = *(const bf16x8*)(RbfT + pos * 32 + ab);
            f32x4 c = {0.f, 0.f, 0.f, 0.f};
            c = __builtin_amdgcn_mfma_f32_16x16x32_bf16(afrag, bfrag, c, 0, 0, 0);
            const int side = pos >> 10;
            const int ij   = pos & 1023;
            const int i    = ij >> 5;
            const int soff = side * 1024 + (ij ^ ((i & 7) << 3));
#pragma unroll
            for (int r = 0; r < 4; ++r)
                F_lds[(ebase + r) * 2048 + soff] = f2bf(c[r]);
        }
    }
    __syncthreads();

    const int r31 = lane & 31;
    const int hi  = lane >> 5;
    const int kb  = hi * 8;
    unsigned short* dxb = dx_lds + wv * 1024;

#pragma unroll 1
    for (int sub = 0; sub < 2; ++sub) {
        const int el = wv * 2 + sub;
        const int e  = e0 + el;
        int src, dst;
        decode_edge(eidx_raw, use64, e, src, dst);
        if ((unsigned)src >= NN || (unsigned)dst >= NN) continue;

        const float* xl = x + (size_t)src * 1024 + r31;
        const float* xr = x + (size_t)dst * 1024 + r31;
        bf16x8 xlf0, xlf1, xrf0, xrf1;
#pragma unroll
        for (int j = 0; j < 8; ++j) {
            xlf0[j] = (short)f2bf(xl[(kb + j) * 32]);
            xlf1[j] = (short)f2bf(xl[(16 + kb + j) * 32]);
            xrf0[j] = (short)f2bf(-xr[(kb + j) * 32]);
            xrf1[j] = (short)f2bf(-xr[(16 + kb + j) * 32]);
        }
        const unsigned short* Fl = F_lds + el * 2048;
        const unsigned short* Fr = Fl + 1024;
        const int rbase = r31 * 32;
        const int rsw   = (r31 & 7) << 3;
        bf16x8 fl0 = *(const bf16x8*)(Fl + ((rbase + kb) ^ rsw));
        bf16x8 fl1 = *(const bf16x8*)(Fl + ((rbase + 16 + kb) ^ rsw));
        bf16x8 fr0 = *(const bf16x8*)(Fr + ((rbase + kb) ^ rsw));
        bf16x8 fr1 = *(const bf16x8*)(Fr + ((rbase + 16 + kb) ^ rsw));

        f32x16 dacc;
#pragma unroll
        for (int r = 0; r < 16; ++r) dacc[r] = 0.f;
        dacc = __builtin_amdgcn_mfma_f32_32x32x16_bf16(fl0, xlf0, dacc, 0, 0, 0);
        dacc = __builtin_amdgcn_mfma_f32_32x32x16_bf16(fl1, xlf1, dacc, 0, 0, 0);
        dacc = __builtin_amdgcn_mfma_f32_32x32x16_bf16(fr0, xrf0, dacc, 0, 0, 0);
        dacc = __builtin_amdgcn_mfma_f32_32x32x16_bf16(fr1, xrf1, dacc, 0, 0, 0);

#pragma unroll
        for (int r = 0; r < 16; ++r) {
            const int row = (r & 3) + 8 * (r >> 2) + 4 * hi;
            dxb[row * 32 + r31] = f2bf(dacc[r]);
        }
        bf16x8 dxf0, dxf1;
#pragma unroll
        for (int j = 0; j < 8; ++j) {
            dxf0[j] = (short)dxb[(kb + j) * 32 + r31];
            dxf1[j] = (short)dxb[(16 + kb + j) * 32 + r31];
        }

        bf16x8 flT0, flT1;
#pragma unroll
        for (int j = 0; j < 8; ++j) {
            const int k0 = kb + j, k1 = 16 + kb + j;
            flT0[j] = (short)Fl[(k0 * 32 + r31) ^ ((k0 & 7) << 3)];
            flT1[j] = (short)Fl[(k1 * 32 + r31) ^ ((k1 & 7) << 3)];
        }
        f32x16 yl;
#pragma unroll
        for (int r = 0; r < 16; ++r) yl[r] = 0.f;
        yl = __builtin_amdgcn_mfma_f32_32x32x16_bf16(flT0, dxf0, yl, 0, 0, 0);
        yl = __builtin_amdgcn_mfma_f32_32x32x16_bf16(flT1, dxf1, yl, 0, 0, 0);
        float* outs = out + (size_t)src * 1024 + r31;
#pragma unroll
        for (int r = 0; r < 16; ++r) {
            const int row = (r & 3) + 8 * (r >> 2) + 4 * hi;
            atomicAdd(outs + row * 32, yl[r]);
        }

        bf16x8 frT0, frT1;
#pragma unroll
        for (int j = 0; j < 8; ++j) {
            const int k0 = kb + j, k1 = 16 + kb + j;
            frT0[j] = (short)Fr[(k0 * 32 + r31) ^ ((k0 & 7) << 3)];
            frT1[j] = (short)Fr[(k1 * 32 + r31) ^ ((k1 & 7) << 3)];
        }
        f32x16 yr;
#pragma unroll
        for (int r = 0; r < 16; ++r) yr[r] = 0.f;
        yr = __builtin_amdgcn_mfma_f32_32x32x16_bf16(frT0, dxf0, yr, 0, 0, 0);
        yr = __builtin_amdgcn_mfma_f32_32x32x16_bf16(frT1, dxf1, yr, 0, 0, 0);
        float* outd = out + (size_t)dst * 1024 + r31;
#pragma unroll
        for (int r = 0; r < 16; ++r) {
            const int row = (r & 3) + 8 * (r >> 2) + 4 * hi;
            atomicAdd(outd + row * 32, -yr[r]);
        }
    }
}

extern "C" void kernel_launch(void* const* d_in, const int* in_sizes, int n_in,
                              void* d_out, int out_size, void* d_ws, size_t ws_size,
                              hipStream_t stream) {
    const float* x  = (const float*)d_in[0];
    const void* eidx = d_in[1];
    const float* ea = (const float*)d_in[2];
    const float* R  = (const float*)d_in[3];
    float* out = (float*)d_out;
    char* ws = (char*)d_ws;

    unsigned short* RbfT = (unsigned short*)(ws + WS_RBFT);
    int* flag = (int*)(ws + WS_FLAG);

    prep_rbf_kernel<<<256, 256, 0, stream>>>(R, RbfT, flag);
    detect_kernel<<<(NE + 255) / 256, 256, 0, stream>>>((const unsigned*)eidx, flag);

    if (ws_size >= WS_CSR_END) {
        unsigned* off = (unsigned*)(ws + WS_OFF);
        unsigned* cur = (unsigned*)(ws + WS_CUR);
        unsigned* cnt = (unsigned*)(ws + WS_CNT);
        unsigned* inc = (unsigned*)(ws + WS_INC);
        unsigned* nodeOf = (unsigned*)(ws + WS_NODE);

        hipMemsetAsync(cnt, 0, 4u * NN, stream);
        count_kernel<<<(NE + 255) / 256, 256, 0, stream>>>(eidx, flag, cnt);
        scan_kernel<<<1, 1024, 0, stream>>>(cnt, off, cur);
        scatter_kernel<<<(NE + 255) / 256, 256, 0, stream>>>(eidx, flag, cur, inc, nodeOf);

        if (ws_size >= WS_PB_END) {
            unsigned short* xT = (unsigned short*)(ws + WS_XT);
            unsigned short* pbuf = (unsigned short*)(ws + WS_PB);
            xpose_kernel<<<NN / 4, 256, 0, stream>>>(x, xT);
            sheaf_inc<<<PGRID, 256, 0, stream>>>(xT, eidx, ea, RbfT, flag, off, inc, nodeOf, out, pbuf);
            combine_kernel<<<NN, 256, 0, stream>>>(off, nodeOf, pbuf, out);
        } else if (ws_size >= WS_XT_END) {
            unsigned short* xT = (unsigned short*)(ws + WS_XT);
            xpose_kernel<<<NN / 4, 256, 0, stream>>>(x, xT);
            sheaf_node<true><<<NN, 256, 0, stream>>>(x, xT, eidx, ea, RbfT, flag, off, inc, out);
        } else {
            sheaf_node<false><<<NN, 256, 0, stream>>>(x, nullptr, eidx, ea, RbfT, flag, off, inc, out);
        }
    } else {
        hipMemsetAsync(d_out, 0, (size_t)out_size * sizeof(float), stream);
        sheaf_atomic<<<NE / 16, 512, 0, stream>>>(x, eidx, ea, RbfT, flag, out);
    }
}